// Round 1
// baseline (316.842 us; speedup 1.0000x reference)
//
#include <hip/hip_runtime.h>

#define BB 32
#define CC 512
#define KK 128
#define HW 16384  // 128*128

// ---------------------------------------------------------------------------
// Pass 1: per-(b,c) channel abs-max. One 256-thread block per channel.
// Each thread reads 16 float4 (64 floats), coalesced stride-256.
// ---------------------------------------------------------------------------
__global__ __launch_bounds__(256) void scores_kernel(const float* __restrict__ x,
                                                     float* __restrict__ scores) {
    const int ch = blockIdx.x;  // b*CC + c
    const float4* p = reinterpret_cast<const float4*>(x) + (size_t)ch * (HW / 4);
    const int tid = threadIdx.x;

    float m = 0.0f;
#pragma unroll
    for (int i = 0; i < 16; ++i) {
        float4 v = p[tid + i * 256];
        m = fmaxf(m, fmaxf(fmaxf(fabsf(v.x), fabsf(v.y)),
                           fmaxf(fabsf(v.z), fabsf(v.w))));
    }
    // wave (64-lane) reduction
#pragma unroll
    for (int off = 32; off > 0; off >>= 1)
        m = fmaxf(m, __shfl_down(m, off, 64));

    __shared__ float smax[4];
    const int wave = tid >> 6;
    if ((tid & 63) == 0) smax[wave] = m;
    __syncthreads();
    if (tid == 0)
        scores[ch] = fmaxf(fmaxf(smax[0], smax[1]), fmaxf(smax[2], smax[3]));
}

// ---------------------------------------------------------------------------
// Pass 2: per-batch top-K + softmax weights. One 512-thread block per batch.
// Bitonic sort of (score desc, idx asc) — strict total order, matches
// jax.lax.top_k ordering. Softmax Z cancels under normalization:
//   w_k = exp(s_k - s_max) / sum_{j in topk} exp(s_j - s_max)
// ---------------------------------------------------------------------------
__global__ __launch_bounds__(512) void topk_kernel(const float* __restrict__ scores,
                                                   int* __restrict__ topk_idx,
                                                   float* __restrict__ wout) {
    const int b = blockIdx.x;
    const int tid = threadIdx.x;  // 0..511

    __shared__ float s[CC];
    __shared__ int idx[CC];
    __shared__ float red[8];

    s[tid] = scores[b * CC + tid];
    idx[tid] = tid;
    __syncthreads();

    // bitonic sort, descending by score, ties -> ascending index
    for (int k = 2; k <= CC; k <<= 1) {
        for (int j = k >> 1; j > 0; j >>= 1) {
            const int ixj = tid ^ j;
            if (ixj > tid) {
                float sa = s[tid], sb = s[ixj];
                int ia = idx[tid], ib = idx[ixj];
                // a_first: element at tid should precede element at ixj
                const bool a_first = (sa > sb) || (sa == sb && ia < ib);
                const bool desc_seg = ((tid & k) == 0);
                const bool do_swap = desc_seg ? !a_first : a_first;
                if (do_swap) {
                    s[tid] = sb; s[ixj] = sa;
                    idx[tid] = ib; idx[ixj] = ia;
                }
            }
            __syncthreads();
        }
    }

    const float smaxv = s[0];  // global max (sorted descending)
    float e = (tid < KK) ? expf(s[tid] - smaxv) : 0.0f;

    // block-wide sum of e (only waves 0,1 contribute nonzero)
    float esum = e;
#pragma unroll
    for (int off = 32; off > 0; off >>= 1)
        esum += __shfl_down(esum, off, 64);
    const int wave = tid >> 6;
    if ((tid & 63) == 0) red[wave] = esum;
    __syncthreads();
    if (tid < KK) {
        float total = 0.0f;
#pragma unroll
        for (int wv = 0; wv < 8; ++wv) total += red[wv];
        total = fmaxf(total, 1e-12f);
        topk_idx[b * KK + tid] = idx[tid];
        wout[b * KK + tid] = e / total;
    }
}

// ---------------------------------------------------------------------------
// Pass 3: gather selected channels scaled by weight. One 256-thread block
// per (b,k) output channel; float4 streaming copy.
// ---------------------------------------------------------------------------
__global__ __launch_bounds__(256) void gather_kernel(const float* __restrict__ x,
                                                     const int* __restrict__ topk_idx,
                                                     const float* __restrict__ w,
                                                     float* __restrict__ out) {
    const int bk = blockIdx.x;  // b*KK + k
    const int b = bk >> 7;
    const int c = topk_idx[bk];
    const float wv = w[bk];

    const float4* src = reinterpret_cast<const float4*>(x) +
                        ((size_t)(b * CC + c)) * (HW / 4);
    float4* dst = reinterpret_cast<float4*>(out) + (size_t)bk * (HW / 4);
    const int tid = threadIdx.x;

#pragma unroll
    for (int i = 0; i < 16; ++i) {
        float4 v = src[tid + i * 256];
        v.x *= wv; v.y *= wv; v.z *= wv; v.w *= wv;
        dst[tid + i * 256] = v;
    }
}

extern "C" void kernel_launch(void* const* d_in, const int* in_sizes, int n_in,
                              void* d_out, int out_size, void* d_ws, size_t ws_size,
                              hipStream_t stream) {
    const float* x = (const float*)d_in[0];
    float* out = (float*)d_out;

    float* scores = (float*)d_ws;                                   // BB*CC floats = 64 KB
    int* idx = (int*)((char*)d_ws + BB * CC * sizeof(float));       // BB*KK ints  = 16 KB
    float* w = (float*)((char*)d_ws + BB * CC * sizeof(float) +
                        BB * KK * sizeof(int));                     // BB*KK floats= 16 KB

    scores_kernel<<<BB * CC, 256, 0, stream>>>(x, scores);
    topk_kernel<<<BB, CC, 0, stream>>>(scores, idx, w);
    gather_kernel<<<BB * KK, 256, 0, stream>>>(x, idx, w, out);
}

// Round 2
// 269.025 us; speedup vs baseline: 1.1777x; 1.1777x over previous
//
#include <hip/hip_runtime.h>

#define BB 32
#define CC 512
#define KK 128
#define HW 16384  // 128*128

typedef float f32x4 __attribute__((ext_vector_type(4)));

// ---------------------------------------------------------------------------
// Pass 1: per-(b,c) channel abs-max. One 256-thread block per channel.
// Each thread reads 16 float4 (64 floats), coalesced; nontemporal (pure
// stream, never re-read at this granularity before eviction).
// ---------------------------------------------------------------------------
__global__ __launch_bounds__(256) void scores_kernel(const float* __restrict__ x,
                                                     float* __restrict__ scores) {
    const int ch = blockIdx.x;  // b*CC + c
    const f32x4* p = reinterpret_cast<const f32x4*>(x) + (size_t)ch * (HW / 4);
    const int tid = threadIdx.x;

    float m = 0.0f;
#pragma unroll
    for (int i = 0; i < 16; ++i) {
        f32x4 v = __builtin_nontemporal_load(&p[tid + i * 256]);
        m = fmaxf(m, fmaxf(fmaxf(fabsf(v.x), fabsf(v.y)),
                           fmaxf(fabsf(v.z), fabsf(v.w))));
    }
    // wave (64-lane) reduction
#pragma unroll
    for (int off = 32; off > 0; off >>= 1)
        m = fmaxf(m, __shfl_down(m, off, 64));

    __shared__ float smax[4];
    const int wave = tid >> 6;
    if ((tid & 63) == 0) smax[wave] = m;
    __syncthreads();
    if (tid == 0)
        scores[ch] = fmaxf(fmaxf(smax[0], smax[1]), fmaxf(smax[2], smax[3]));
}

// ---------------------------------------------------------------------------
// Pass 2: per-batch top-K + softmax weights. One 512-thread block per batch.
// Bitonic sort (score desc, idx asc) — strict total order, matches
// jax.lax.top_k. Softmax Z cancels under normalization.
// ---------------------------------------------------------------------------
__global__ __launch_bounds__(512) void topk_kernel(const float* __restrict__ scores,
                                                   int* __restrict__ topk_idx,
                                                   float* __restrict__ wout) {
    const int b = blockIdx.x;
    const int tid = threadIdx.x;  // 0..511

    __shared__ float s[CC];
    __shared__ int idx[CC];
    __shared__ float red[8];

    s[tid] = scores[b * CC + tid];
    idx[tid] = tid;
    __syncthreads();

    for (int k = 2; k <= CC; k <<= 1) {
        for (int j = k >> 1; j > 0; j >>= 1) {
            const int ixj = tid ^ j;
            if (ixj > tid) {
                float sa = s[tid], sb = s[ixj];
                int ia = idx[tid], ib = idx[ixj];
                const bool a_first = (sa > sb) || (sa == sb && ia < ib);
                const bool desc_seg = ((tid & k) == 0);
                const bool do_swap = desc_seg ? !a_first : a_first;
                if (do_swap) {
                    s[tid] = sb; s[ixj] = sa;
                    idx[tid] = ib; idx[ixj] = ia;
                }
            }
            __syncthreads();
        }
    }

    const float smaxv = s[0];
    float e = (tid < KK) ? expf(s[tid] - smaxv) : 0.0f;

    float esum = e;
#pragma unroll
    for (int off = 32; off > 0; off >>= 1)
        esum += __shfl_down(esum, off, 64);
    const int wave = tid >> 6;
    if ((tid & 63) == 0) red[wave] = esum;
    __syncthreads();
    if (tid < KK) {
        float total = 0.0f;
#pragma unroll
        for (int wv = 0; wv < 8; ++wv) total += red[wv];
        total = fmaxf(total, 1e-12f);
        topk_idx[b * KK + tid] = idx[tid];
        wout[b * KK + tid] = e / total;
    }
}

// ---------------------------------------------------------------------------
// Pass 3: gather selected channels scaled by weight. One 256-thread block
// per (b,k). Register-staged: all 16 loads issued before any store
// (maximizes outstanding vmcnt); nontemporal stores (output never re-read).
// Source loads stay cached — ~25% hit the L3 tail of the scores pass.
// ---------------------------------------------------------------------------
__global__ __launch_bounds__(256) void gather_kernel(const float* __restrict__ x,
                                                     const int* __restrict__ topk_idx,
                                                     const float* __restrict__ w,
                                                     float* __restrict__ out) {
    const int bk = blockIdx.x;  // b*KK + k
    const int b = bk >> 7;
    const int c = topk_idx[bk];
    const float wv = w[bk];

    const f32x4* src = reinterpret_cast<const f32x4*>(x) +
                       ((size_t)(b * CC + c)) * (HW / 4);
    f32x4* dst = reinterpret_cast<f32x4*>(out) + (size_t)bk * (HW / 4);
    const int tid = threadIdx.x;

    f32x4 r[16];
#pragma unroll
    for (int i = 0; i < 16; ++i)
        r[i] = src[tid + i * 256];
#pragma unroll
    for (int i = 0; i < 16; ++i) {
        f32x4 v = r[i];
        v.x *= wv; v.y *= wv; v.z *= wv; v.w *= wv;
        __builtin_nontemporal_store(v, &dst[tid + i * 256]);
    }
}

extern "C" void kernel_launch(void* const* d_in, const int* in_sizes, int n_in,
                              void* d_out, int out_size, void* d_ws, size_t ws_size,
                              hipStream_t stream) {
    const float* x = (const float*)d_in[0];
    float* out = (float*)d_out;

    float* scores = (float*)d_ws;                                   // BB*CC floats
    int* idx = (int*)((char*)d_ws + BB * CC * sizeof(float));       // BB*KK ints
    float* w = (float*)((char*)d_ws + BB * CC * sizeof(float) +
                        BB * KK * sizeof(int));                     // BB*KK floats

    scores_kernel<<<BB * CC, 256, 0, stream>>>(x, scores);
    topk_kernel<<<BB, CC, 0, stream>>>(scores, idx, w);
    gather_kernel<<<BB * KK, 256, 0, stream>>>(x, idx, w, out);
}